// Round 6
// baseline (2031.311 us; speedup 1.0000x reference)
//
#include <hip/hip_runtime.h>
#include <math.h>

// ---------------------------------------------------------------------------
// Weight transposes: OIHW -> wt[(ci*KK+tap)*COUT + co]  (contiguous in co so
// conv kernels read weights as wave-uniform float4 -> s_load_dwordx4).
// ---------------------------------------------------------------------------
__global__ void transpose_w(const float* __restrict__ w, float* __restrict__ wt,
                            int CIN, int COUT, int KK) {
  int i = blockIdx.x * 256 + threadIdx.x;
  int total = CIN * COUT * KK;
  if (i < total) {
    int co = i / (CIN * KK);
    int r = i % (CIN * KK);              // ci*KK + tap
    wt[(size_t)r * COUT + co] = w[i];
  }
}
// torch tconv [Cin][Cout][4][4] -> wt[(ci*16+kk)*COUT + co]
__global__ void transpose_wt(const float* __restrict__ w, float* __restrict__ wt,
                             int CIN, int COUT) {
  int i = blockIdx.x * 256 + threadIdx.x;
  int total = CIN * COUT * 16;
  if (i < total) {
    int ci = i / (COUT * 16);
    int rem = i % (COUT * 16);
    int co = rem / 16;
    int kk = rem % 16;
    wt[((size_t)ci * 16 + kk) * COUT + co] = w[i];
  }
}

// ---------------------------------------------------------------------------
// Legacy direct conv (global loads) — conv1 (CIN=1) and conv4 (1x1).
// ---------------------------------------------------------------------------
template<int CIN, int COUT, int K, int S, int PAD, int HIN, int WIN,
         int HOUT, int WOUT, bool RELU, int CCH>
__global__ __launch_bounds__(256, 3)
void conv_fwd(const float* __restrict__ x, const float* __restrict__ w,
              const float* __restrict__ bias, float* __restrict__ out) {
  constexpr int NPOS = HOUT * WOUT;
  constexpr int PTILES = NPOS / 1024;
  constexpr int NCH = COUT / CCH;
  constexpr int RSTEP = 256 / WOUT;
  constexpr int ROWS_PER_TILE = 1024 / WOUT;
  static_assert(NPOS % 1024 == 0, "pos tiling");

  int bid = blockIdx.x;
  int cchunk = bid % NCH;
  int ptile = (bid / NCH) % PTILES;
  int n = bid / (NCH * PTILES);
  int co0 = cchunk * CCH;

  __shared__ float wl[CIN * K * K][CCH];
  for (int i = threadIdx.x; i < CIN * K * K * CCH; i += 256) {
    int cc = i % CCH;
    int tap = i / CCH;
    wl[tap][cc] = w[(size_t)(co0 + cc) * (CIN * K * K) + tap];
  }
  __syncthreads();

  int t = threadIdx.x;
  int sx = t % WOUT;
  int syb = ptile * ROWS_PER_TILE + t / WOUT;

  float acc[4][CCH];
#pragma unroll
  for (int j = 0; j < 4; j++)
#pragma unroll
    for (int c = 0; c < CCH; c++) acc[j][c] = 0.f;

  const float* xn = x + (size_t)n * CIN * HIN * WIN;
  int ix0 = sx * S - PAD;

  for (int ci = 0; ci < CIN; ci++) {
    const float* xc = xn + (size_t)ci * HIN * WIN;
#pragma unroll
    for (int ky = 0; ky < K; ky++) {
#pragma unroll
      for (int kx = 0; kx < K; kx++) {
        int ix = ix0 + kx;
        bool xok = (unsigned)ix < WIN;
        float xv[4];
#pragma unroll
        for (int j = 0; j < 4; j++) {
          int iy = (syb + j * RSTEP) * S - PAD + ky;
          bool ok = xok && ((unsigned)iy < HIN);
          xv[j] = ok ? xc[iy * WIN + ix] : 0.f;
        }
        const float* wr = &wl[ci * K * K + ky * K + kx][0];
#pragma unroll
        for (int c = 0; c < CCH; c += 4) {
          float4 wv = *(const float4*)(wr + c);
#pragma unroll
          for (int j = 0; j < 4; j++) {
            acc[j][c + 0] = fmaf(xv[j], wv.x, acc[j][c + 0]);
            acc[j][c + 1] = fmaf(xv[j], wv.y, acc[j][c + 1]);
            acc[j][c + 2] = fmaf(xv[j], wv.z, acc[j][c + 2]);
            acc[j][c + 3] = fmaf(xv[j], wv.w, acc[j][c + 3]);
          }
        }
      }
    }
  }

#pragma unroll
  for (int j = 0; j < 4; j++) {
    int sy = syb + j * RSTEP;
    float* op = out + (((size_t)n * COUT + co0) * HOUT + sy) * WOUT + sx;
#pragma unroll
    for (int c = 0; c < CCH; c++) {
      float v = acc[j][c] + bias[co0 + c];
      if (RELU) v = fmaxf(v, 0.f);
      op[(size_t)c * HOUT * WOUT] = v;
    }
  }
}

// ---------------------------------------------------------------------------
// conv 3x3 s=1 p=1 ReLU on 32x32, scalar weights (transposed wt), row-strip:
// thread owns rows 4*rg..4*rg+3 at column sx -> 18 LDS reads/ci (vs 36).
// Chain order per output: ci -> ky -> kx (bitwise-identical to legacy).
// grid = NB * (COUT/CCH). LDS = CSTG KB staged input only.
// ---------------------------------------------------------------------------
template<int CIN, int COUT, int CCH, int CSTG>
__global__ __launch_bounds__(256)
void conv3x3_s(const float* __restrict__ x, const float* __restrict__ wt,
               const float* __restrict__ bias, float* __restrict__ out) {
  constexpr int NCH = COUT / CCH;
  int bid = blockIdx.x;
  int cchunk = bid % NCH;
  int n = bid / NCH;
  int co0 = cchunk * CCH;

  __shared__ float xs[CSTG * 1024];
  int t = threadIdx.x;
  int sx = t & 31;
  int rg = t >> 5;                   // rows 4*rg .. 4*rg+3

  float acc[4][CCH];
#pragma unroll
  for (int j = 0; j < 4; j++)
#pragma unroll
    for (int c = 0; c < CCH; c++) acc[j][c] = 0.f;

  const float* xn = x + (size_t)n * CIN * 1024;

  for (int cg = 0; cg < CIN / CSTG; cg++) {
    __syncthreads();
#pragma unroll
    for (int k = 0; k < CSTG; k++)
      *(float4*)(xs + k * 1024 + t * 4) =
          *(const float4*)(xn + (size_t)(cg * CSTG + k) * 1024 + t * 4);
    __syncthreads();

#pragma unroll
    for (int c4 = 0; c4 < CSTG; c4++) {
      int ci = cg * CSTG + c4;
      const float* xc = xs + c4 * 1024;
      float xv[6][3];
#pragma unroll
      for (int r = 0; r < 6; r++) {
        int iy = 4 * rg - 1 + r;
        bool yok = (unsigned)iy < 32;
#pragma unroll
        for (int cx = 0; cx < 3; cx++) {
          int ix = sx - 1 + cx;
          bool ok = yok && ((unsigned)ix < 32);
          float v = xc[ok ? iy * 32 + ix : 0];
          xv[r][cx] = ok ? v : 0.f;
        }
      }
#pragma unroll
      for (int ky = 0; ky < 3; ky++) {
#pragma unroll
        for (int kx = 0; kx < 3; kx++) {
          const float* wr = wt + (size_t)(ci * 9 + ky * 3 + kx) * COUT + co0;
#pragma unroll
          for (int c = 0; c < CCH; c += 4) {
            float4 wv = *(const float4*)(wr + c);
#pragma unroll
            for (int j = 0; j < 4; j++) {
              float xx = xv[j + ky][kx];
              acc[j][c + 0] = fmaf(xx, wv.x, acc[j][c + 0]);
              acc[j][c + 1] = fmaf(xx, wv.y, acc[j][c + 1]);
              acc[j][c + 2] = fmaf(xx, wv.z, acc[j][c + 2]);
              acc[j][c + 3] = fmaf(xx, wv.w, acc[j][c + 3]);
            }
          }
        }
      }
    }
  }

#pragma unroll
  for (int j = 0; j < 4; j++) {
    int sy = 4 * rg + j;
    float* op = out + (((size_t)n * COUT + co0) * 32 + sy) * 32 + sx;
#pragma unroll
    for (int c = 0; c < CCH; c++) {
      float v = acc[j][c] + bias[co0 + c];
      v = fmaxf(v, 0.f);
      op[(size_t)c * 1024] = v;
    }
  }
}

// ---------------------------------------------------------------------------
// conv 4x4 s=2 p=1 ReLU, 64x64 -> 32x32, scalar weights (transposed wt).
// Column-position layout (rows sy0, +8, +16, +24). CSTG channels staged.
// grid = NB * (COUT/CCH).
// ---------------------------------------------------------------------------
template<int CIN, int COUT, int CCH, int CSTG>
__global__ __launch_bounds__(256)
void conv4x4s2_s(const float* __restrict__ x, const float* __restrict__ wt,
                 const float* __restrict__ bias, float* __restrict__ out) {
  constexpr int NCH = COUT / CCH;
  int bid = blockIdx.x;
  int cchunk = bid % NCH;
  int n = bid / NCH;
  int co0 = cchunk * CCH;

  __shared__ float xs[CSTG * 4096];
  int t = threadIdx.x;
  int sx = t & 31;
  int sy0 = t >> 5;
  int ix0 = 2 * sx - 1;

  float acc[4][CCH];
#pragma unroll
  for (int j = 0; j < 4; j++)
#pragma unroll
    for (int c = 0; c < CCH; c++) acc[j][c] = 0.f;

  const float* xn = x + (size_t)n * CIN * 4096;

  for (int cg = 0; cg < CIN / CSTG; cg++) {
    __syncthreads();
#pragma unroll
    for (int k = 0; k < CSTG * 4; k++)
      *(float4*)(xs + k * 1024 + t * 4) =
          *(const float4*)(xn + (size_t)cg * CSTG * 4096 + k * 1024 + t * 4);
    __syncthreads();

#pragma unroll
    for (int c4 = 0; c4 < CSTG; c4++) {
      int ci = cg * CSTG + c4;
      const float* xc = xs + c4 * 4096;
#pragma unroll
      for (int ky = 0; ky < 4; ky++) {
#pragma unroll
        for (int kx = 0; kx < 4; kx++) {
          int ix = ix0 + kx;
          bool xok = (unsigned)ix < 64;
          float xv[4];
#pragma unroll
          for (int j = 0; j < 4; j++) {
            int iy = 2 * (sy0 + j * 8) - 1 + ky;
            bool ok = xok && ((unsigned)iy < 64);
            float v = xc[ok ? iy * 64 + ix : 0];
            xv[j] = ok ? v : 0.f;
          }
          const float* wr = wt + (size_t)(ci * 16 + ky * 4 + kx) * COUT + co0;
#pragma unroll
          for (int c = 0; c < CCH; c += 4) {
            float4 wv = *(const float4*)(wr + c);
#pragma unroll
            for (int j = 0; j < 4; j++) {
              acc[j][c + 0] = fmaf(xv[j], wv.x, acc[j][c + 0]);
              acc[j][c + 1] = fmaf(xv[j], wv.y, acc[j][c + 1]);
              acc[j][c + 2] = fmaf(xv[j], wv.z, acc[j][c + 2]);
              acc[j][c + 3] = fmaf(xv[j], wv.w, acc[j][c + 3]);
            }
          }
        }
      }
    }
  }

#pragma unroll
  for (int j = 0; j < 4; j++) {
    int sy = sy0 + j * 8;
    float* op = out + (((size_t)n * COUT + co0) * 32 + sy) * 32 + sx;
#pragma unroll
    for (int c = 0; c < CCH; c++) {
      float v = acc[j][c] + bias[co0 + c];
      v = fmaxf(v, 0.f);
      op[(size_t)c * 1024] = v;
    }
  }
}

// ---------------------------------------------------------------------------
// Transposed conv k=4 s=2 p=1 ReLU (dect1), parity-decomposed, scalar
// weights (wdt[(ci*16+kk)*COUT+co]), row-strip: 10 LDS reads/ci (vs 16).
// Chain order per output: ci -> kyi -> kxi (identical to round-5 kernel).
// grid = NB * 4 * (COUT/CCH). in 32x32, out 64x64.
// ---------------------------------------------------------------------------
template<int CIN, int COUT, int CCH, int CSTG>
__global__ __launch_bounds__(256)
void convt_s(const float* __restrict__ x, const float* __restrict__ wdt,
             const float* __restrict__ bias, float* __restrict__ out) {
  constexpr int NCH = COUT / CCH;
  int bid = blockIdx.x;
  int cchunk = bid % NCH;
  int par = (bid / NCH) & 3;
  int n = bid / (NCH * 4);
  int py = par >> 1, px = par & 1;
  int co0 = cchunk * CCH;
  int ky0 = (py + 1) & 1, kx0 = (px + 1) & 1;
  int ay = (py + 1 - ky0) >> 1;
  int ax = (px + 1 - kx0) >> 1;

  __shared__ float xs[CSTG * 1024];
  int t = threadIdx.x;
  int sx = t & 31;
  int rg = t >> 5;                  // rows 4*rg .. 4*rg+3

  float acc[4][CCH];
#pragma unroll
  for (int j = 0; j < 4; j++)
#pragma unroll
    for (int c = 0; c < CCH; c++) acc[j][c] = 0.f;

  const float* xn = x + (size_t)n * CIN * 1024;

  for (int cg = 0; cg < CIN / CSTG; cg++) {
    __syncthreads();
#pragma unroll
    for (int k = 0; k < CSTG; k++)
      *(float4*)(xs + k * 1024 + t * 4) =
          *(const float4*)(xn + (size_t)(cg * CSTG + k) * 1024 + t * 4);
    __syncthreads();

#pragma unroll
    for (int c4 = 0; c4 < CSTG; c4++) {
      int ci = cg * CSTG + c4;
      const float* xc = xs + c4 * 1024;
      // rows 4rg+ay-1 .. 4rg+ay+3 (5), cols sx+ax-1, sx+ax (2)
      float xv[5][2];
#pragma unroll
      for (int r = 0; r < 5; r++) {
        int iy = 4 * rg + ay - 1 + r;
        bool yok = (unsigned)iy < 32;
#pragma unroll
        for (int cx = 0; cx < 2; cx++) {
          int ix = sx + ax - 1 + cx;
          bool ok = yok && ((unsigned)ix < 32);
          float v = xc[ok ? iy * 32 + ix : 0];
          xv[r][cx] = ok ? v : 0.f;
        }
      }
#pragma unroll
      for (int kyi = 0; kyi < 2; kyi++) {
#pragma unroll
        for (int kxi = 0; kxi < 2; kxi++) {
          int kk = (ky0 + 2 * kyi) * 4 + (kx0 + 2 * kxi);
          const float* wr = wdt + (size_t)(ci * 16 + kk) * COUT + co0;
#pragma unroll
          for (int c = 0; c < CCH; c += 4) {
            float4 wv = *(const float4*)(wr + c);
#pragma unroll
            for (int j = 0; j < 4; j++) {
              float xx = xv[j + 1 - kyi][1 - kxi];
              acc[j][c + 0] = fmaf(xx, wv.x, acc[j][c + 0]);
              acc[j][c + 1] = fmaf(xx, wv.y, acc[j][c + 1]);
              acc[j][c + 2] = fmaf(xx, wv.z, acc[j][c + 2]);
              acc[j][c + 3] = fmaf(xx, wv.w, acc[j][c + 3]);
            }
          }
        }
      }
    }
  }

#pragma unroll
  for (int j = 0; j < 4; j++) {
    int sy = 4 * rg + j;
    int oy = 2 * sy + py;
    int ox = 2 * sx + px;
    float* op = out + (((size_t)n * COUT + co0) * 64 + oy) * 64 + ox;
#pragma unroll
    for (int c = 0; c < CCH; c++) {
      float v = acc[j][c] + bias[co0 + c];
      v = fmaxf(v, 0.f);
      op[(size_t)c * 4096] = v;
    }
  }
}

// ---------------------------------------------------------------------------
// dect2: transposed conv k=4 s=2 p=1, CIN=32, COUT=1, sigmoid; ALL 4
// parities per thread (input read once). in 64x64 -> out 128x128.
// Thread owns input rows 4*r4..4*r4+3 (within its 16-row tile) at col sx,
// computes the 2x2 output quad per input position; float2 packed stores.
// tw2 torch layout [ci][1][4][4] is already [(ci*16+kk)] -> no transpose.
// grid = NB * 4 tiles.
// ---------------------------------------------------------------------------
__global__ __launch_bounds__(256)
void dect2_full(const float* __restrict__ x, const float* __restrict__ w,
                const float* __restrict__ bias, float* __restrict__ out) {
  int ptile = blockIdx.x & 3;
  int n = blockIdx.x >> 2;
  int y0 = ptile * 16;

  __shared__ float xs[4][1152];      // rows y0-1..y0+16 (18) x 64 cols
  int t = threadIdx.x;
  int sx = t & 63;
  int r4 = t >> 6;                   // rows y0 + 4*r4 + {0..3}

  float acc[4][4];                   // [j][par], par = py*2+px
#pragma unroll
  for (int j = 0; j < 4; j++)
#pragma unroll
    for (int p = 0; p < 4; p++) acc[j][p] = 0.f;

  const float* xn = x + (size_t)n * 32 * 4096;

  for (int cg = 0; cg < 8; cg++) {   // 4 channels per stage
    __syncthreads();
    for (int idx = t; idx < 4 * 1152; idx += 256) {
      int ch = idx / 1152;
      int rem = idx % 1152;
      int iy = y0 - 1 + rem / 64;
      int ix = rem & 63;
      bool ok = (unsigned)iy < 64;
      xs[ch][rem] = ok ? xn[(size_t)(cg * 4 + ch) * 4096 + iy * 64 + ix] : 0.f;
    }
    __syncthreads();

#pragma unroll
    for (int c4 = 0; c4 < 4; c4++) {
      int ci = cg * 4 + c4;
      const float* xc = &xs[c4][0];
      // slab rows 4*r4 + r (r=0..5) = global rows y0+4r4-1+r; cols sx-1..sx+1
      float xv[6][3];
#pragma unroll
      for (int r = 0; r < 6; r++) {
        int srow = 4 * r4 + r;
#pragma unroll
        for (int cx = 0; cx < 3; cx++) {
          int ix = sx - 1 + cx;
          bool ok = (unsigned)ix < 64;
          float v = xc[ok ? srow * 64 + ix : 0];
          xv[r][cx] = ok ? v : 0.f;
        }
      }
      float w16[16];
#pragma unroll
      for (int q = 0; q < 4; q++) {
        float4 ww = *(const float4*)(w + ci * 16 + 4 * q);
        w16[4 * q + 0] = ww.x; w16[4 * q + 1] = ww.y;
        w16[4 * q + 2] = ww.z; w16[4 * q + 3] = ww.w;
      }
#pragma unroll
      for (int py = 0; py < 2; py++) {
#pragma unroll
        for (int px = 0; px < 2; px++) {
          int par = py * 2 + px;
          int ky0 = (py + 1) & 1, kx0 = (px + 1) & 1;
          int ay = (py + 1 - ky0) >> 1;
          int ax = (px + 1 - kx0) >> 1;
#pragma unroll
          for (int kyi = 0; kyi < 2; kyi++) {
#pragma unroll
            for (int kxi = 0; kxi < 2; kxi++) {
              float wv = w16[(ky0 + 2 * kyi) * 4 + (kx0 + 2 * kxi)];
#pragma unroll
              for (int j = 0; j < 4; j++) {
                float xx = xv[j + ay + 1 - kyi][ax + 1 - kxi];
                acc[j][par] = fmaf(xx, wv, acc[j][par]);
              }
            }
          }
        }
      }
    }
  }

  float b0 = bias[0];
#pragma unroll
  for (int j = 0; j < 4; j++) {
    int iy = y0 + 4 * r4 + j;
#pragma unroll
    for (int py = 0; py < 2; py++) {
      float v0 = acc[j][py * 2 + 0] + b0;
      float v1 = acc[j][py * 2 + 1] + b0;
      float2 o;
      o.x = 1.f / (1.f + expf(-v0));
      o.y = 1.f / (1.f + expf(-v1));
      int oy = 2 * iy + py;
      *(float2*)(out + (size_t)n * 16384 + oy * 128 + 2 * sx) = o;
    }
  }
}

// ---------------------------------------------------------------------------
__global__ void cbn_prep(const float* __restrict__ cb, float* __restrict__ cbn) {
#pragma clang fp contract(off)
  int k = blockIdx.x * 256 + threadIdx.x;
  if (k < 512) {
    float m[32];
#pragma unroll
    for (int d = 0; d < 32; d++) {
      float c = cb[k * 32 + d];
      m[d] = c * c;
    }
    float r[8];
#pragma unroll
    for (int j = 0; j < 8; j++)
      r[j] = ((m[j] + m[8 + j]) + m[16 + j]) + m[24 + j];
    cbn[k] = ((r[0] + r[1]) + (r[2] + r[3])) + ((r[4] + r[5]) + (r[6] + r[7]));
  }
}

// ---------------------------------------------------------------------------
// VQ: np-exact arithmetic (round-4 verified, per-pixel chains UNCHANGED).
// Now 1 px/thread (grid NB*4) with codebook read via wave-uniform loads
// (scalar path) instead of 64KB LDS -> better occupancy, no LDS cap.
// ---------------------------------------------------------------------------
__global__ __launch_bounds__(256)
void vq_kernel(const float* __restrict__ z, const float* __restrict__ cb,
               const float* __restrict__ cbn, float* __restrict__ qz,
               float* __restrict__ loss) {
  int tid = threadIdx.x;
  int n = blockIdx.x >> 2;
  int p = (blockIdx.x & 3) * 256 + tid;
  const float* zn = z + (size_t)n * 32768;

  float zv[32];
#pragma unroll
  for (int d = 0; d < 32; d++) zv[d] = zn[(size_t)d * 1024 + p];

  float zz;
  {
#pragma clang fp contract(off)
    float m[32];
#pragma unroll
    for (int d = 0; d < 32; d++) m[d] = zv[d] * zv[d];
    float r[8];
#pragma unroll
    for (int j = 0; j < 8; j++)
      r[j] = ((m[j] + m[8 + j]) + m[16 + j]) + m[24 + j];
    zz = ((r[0] + r[1]) + (r[2] + r[3])) + ((r[4] + r[5]) + (r[6] + r[7]));
  }

  float best = 3.4e38f;
  int bk = 0;
  for (int k4 = 0; k4 < 512; k4 += 4) {
    float4 cn = *(const float4*)(cbn + k4);
    float da[4];
#pragma unroll
    for (int u = 0; u < 4; u++) da[u] = 0.f;
#pragma unroll
    for (int d = 0; d < 32; d += 4) {
#pragma unroll
      for (int u = 0; u < 4; u++) {
        float4 c = *(const float4*)(cb + (size_t)(k4 + u) * 32 + d);
        float a = da[u];
        a = fmaf(zv[d + 0], c.x, a);
        a = fmaf(zv[d + 1], c.y, a);
        a = fmaf(zv[d + 2], c.z, a);
        a = fmaf(zv[d + 3], c.w, a);
        da[u] = a;
      }
    }
#pragma unroll
    for (int u = 0; u < 4; u++) {
      float cnu = (u == 0) ? cn.x : (u == 1) ? cn.y : (u == 2) ? cn.z : cn.w;
      float s;
      {
#pragma clang fp contract(off)
        s = (zz + cnu) - 2.f * da[u];
      }
      int k = k4 + u;
      if (s < best) { best = s; bk = k; }
    }
  }

  float lsum = 0.f;
  float* qn = qz + (size_t)n * 32768;
#pragma unroll
  for (int d = 0; d < 32; d += 4) {
#pragma clang fp contract(off)
    float4 q = *(const float4*)(cb + (size_t)bk * 32 + d);
    float e;
    e = q.x - zv[d + 0]; lsum = fmaf(e, e, lsum);
    e = q.y - zv[d + 1]; lsum = fmaf(e, e, lsum);
    e = q.z - zv[d + 2]; lsum = fmaf(e, e, lsum);
    e = q.w - zv[d + 3]; lsum = fmaf(e, e, lsum);
    qn[(size_t)(d + 0) * 1024 + p] = zv[d + 0] + (q.x - zv[d + 0]);
    qn[(size_t)(d + 1) * 1024 + p] = zv[d + 1] + (q.y - zv[d + 1]);
    qn[(size_t)(d + 2) * 1024 + p] = zv[d + 2] + (q.z - zv[d + 2]);
    qn[(size_t)(d + 3) * 1024 + p] = zv[d + 3] + (q.w - zv[d + 3]);
  }

#pragma unroll
  for (int off = 32; off; off >>= 1) lsum += __shfl_down(lsum, off, 64);
  if ((tid & 63) == 0) atomicAdd(loss, lsum);
}

__global__ void finalize_loss(const float* __restrict__ loss, float* __restrict__ out) {
  if (threadIdx.x == 0) {
    float m = loss[0] / 8388608.f;
    out[0] = m + 0.26f * m;
  }
}

// ---------------------------------------------------------------------------
// Workspace (floats): A = chunk*131072, B = chunk*65536, cbn 512, loss 1,
// wt2 32768, wt3 36864, wd1 18432, wdt1 32768  (~0.5 MB extra).
// Full batch: 201.8 MB. Chunk count from ws_size (constant -> graph-safe).
// ---------------------------------------------------------------------------
extern "C" void kernel_launch(void* const* d_in, const int* in_sizes, int n_in,
                              void* d_out, int out_size, void* d_ws, size_t ws_size,
                              hipStream_t stream) {
  (void)in_sizes; (void)n_in; (void)out_size;
  const float* x   = (const float*)d_in[0];
  const float* ew1 = (const float*)d_in[1];
  const float* eb1 = (const float*)d_in[2];
  const float* ew2 = (const float*)d_in[3];
  const float* eb2 = (const float*)d_in[4];
  const float* ew3 = (const float*)d_in[5];
  const float* eb3 = (const float*)d_in[6];
  const float* ew4 = (const float*)d_in[7];
  const float* eb4 = (const float*)d_in[8];
  const float* cb  = (const float*)d_in[9];
  const float* dw1 = (const float*)d_in[10];
  const float* db1 = (const float*)d_in[11];
  const float* tw1 = (const float*)d_in[12];
  const float* tb1 = (const float*)d_in[13];
  const float* tw2 = (const float*)d_in[14];
  const float* tb2 = (const float*)d_in[15];
  float* out = (float*)d_out;

  auto need = [](size_t c) -> size_t {
    return (c * 196608 + 513 + 32768 + 36864 + 18432 + 32768) * 4;
  };
  int nchunks = 4;
  if (ws_size >= need(256)) nchunks = 1;
  else if (ws_size >= need(128)) nchunks = 2;
  int chunk = 256 / nchunks;

  float* ws = (float*)d_ws;
  float* A = ws;
  float* B = A + (size_t)chunk * 131072;
  float* cbn = B + (size_t)chunk * 65536;
  float* lossacc = cbn + 512;
  float* wt2  = lossacc + 1;
  float* wt3  = wt2 + 32768;
  float* wd1  = wt3 + 36864;
  float* wdt1 = wd1 + 18432;

  float* h1 = A;
  float* h2 = B;
  float* h3 = A;
  float* z  = A + (size_t)chunk * 65536;
  float* qz = A + (size_t)chunk * 98304;
  float* d1 = B;
  float* d2 = A;

  // prep: codebook norms, weight transposes, loss accumulator
  cbn_prep<<<2, 256, 0, stream>>>(cb, cbn);
  transpose_w<<<(32 * 64 * 16 + 255) / 256, 256, 0, stream>>>(ew2, wt2, 32, 64, 16);
  transpose_w<<<(64 * 64 * 9 + 255) / 256, 256, 0, stream>>>(ew3, wt3, 64, 64, 9);
  transpose_w<<<(32 * 64 * 9 + 255) / 256, 256, 0, stream>>>(dw1, wd1, 32, 64, 9);
  transpose_wt<<<(64 * 32 * 16 + 255) / 256, 256, 0, stream>>>(tw1, wdt1, 64, 32);
  (void)hipMemsetAsync(lossacc, 0, 4, stream);

  for (int c = 0; c < nchunks; c++) {
    const float* xc = x + (size_t)c * chunk * 128 * 128;
    float* outc = out + (size_t)c * chunk * 128 * 128;

    conv_fwd<1, 32, 4, 2, 1, 128, 128, 64, 64, true, 16>
        <<<chunk * 4 * 2, 256, 0, stream>>>(xc, ew1, eb1, h1);
    conv4x4s2_s<32, 64, 16, 2>
        <<<chunk * 4, 256, 0, stream>>>(h1, wt2, eb2, h2);
    conv3x3_s<64, 64, 16, 8>
        <<<chunk * 4, 256, 0, stream>>>(h2, wt3, eb3, h3);
    conv_fwd<64, 32, 1, 1, 0, 32, 32, 32, 32, false, 16>
        <<<chunk * 2, 256, 0, stream>>>(h3, ew4, eb4, z);

    vq_kernel<<<chunk * 4, 256, 0, stream>>>(z, cb, cbn, qz, lossacc);

    conv3x3_s<32, 64, 16, 8>
        <<<chunk * 4, 256, 0, stream>>>(qz, wd1, db1, d1);
    convt_s<64, 32, 16, 8>
        <<<chunk * 4 * 2, 256, 0, stream>>>(d1, wdt1, tb1, d2);
    dect2_full<<<chunk * 4, 256, 0, stream>>>(d2, tw2, tb2, outc);
  }

  finalize_loss<<<1, 64, 0, stream>>>(lossacc, out + 4194304);
}